// Round 1
// baseline (901.709 us; speedup 1.0000x reference)
//
#include <hip/hip_runtime.h>

// ---------------------------------------------------------------------------
// 2-layer GCN on MI355X.
//   deg[i]   = (#edges with dst==i) + 1 (self loop)      [reference: from d only]
//   dinv[i]  = rsqrt(deg[i])
//   g        = rowscale(x @ W, dinv)
//   h[i]     = relu(dinv[i] * (g[i] + sum_{s in N(i)} g[s]) + b)
//   out[i]   = h2[i] . Wl + bl   (fused into layer-2 aggregation)
// CSR built on-device each launch (histogram -> scan -> atomic fill).
// ---------------------------------------------------------------------------

__global__ void hist_k(const int* __restrict__ dst, int* __restrict__ cnt, int E) {
    int i = blockIdx.x * blockDim.x + threadIdx.x;
    if (i < E) atomicAdd(&cnt[dst[i]], 1);
}

__global__ void dinv_k(const int* __restrict__ cnt, float* __restrict__ dinv, int n) {
    int i = blockIdx.x * blockDim.x + threadIdx.x;
    if (i < n) dinv[i] = rsqrtf((float)(cnt[i] + 1));
}

// Tile = 2048 (256 thr x 8). Per-tile exclusive scan -> off, tile totals -> tsum.
__global__ void scan1_k(const int* __restrict__ cnt, int* __restrict__ off,
                        int* __restrict__ tsum, int n) {
    __shared__ int lsum[256];
    int tile = blockIdx.x;
    int t = threadIdx.x;
    int base = tile * 2048 + t * 8;
    int v[8];
    int s = 0;
#pragma unroll
    for (int u = 0; u < 8; u++) {
        int i = base + u;
        int c = (i < n) ? cnt[i] : 0;
        v[u] = s;
        s += c;
    }
    lsum[t] = s;
    __syncthreads();
    for (int d = 1; d < 256; d <<= 1) {
        int x = (t >= d) ? lsum[t - d] : 0;
        __syncthreads();
        lsum[t] += x;
        __syncthreads();
    }
    int excl = (t > 0) ? lsum[t - 1] : 0;
    if (t == 255) tsum[tile] = lsum[255];
#pragma unroll
    for (int u = 0; u < 8; u++) {
        int i = base + u;
        if (i < n) off[i] = excl + v[u];
    }
}

// Add tile prefix; also write cur[] (= cnt array reused) and off[n] = E.
__global__ void scan2_k(int* __restrict__ off, int* __restrict__ cur,
                        const int* __restrict__ tsum, int n, int ntiles) {
    __shared__ int pre;
    int tile = blockIdx.x;
    int t = threadIdx.x;
    if (t == 0) {
        int s = 0;
        for (int b = 0; b < tile; b++) s += tsum[b];
        pre = s;
    }
    __syncthreads();
    int base = tile * 2048 + t * 8;
#pragma unroll
    for (int u = 0; u < 8; u++) {
        int i = base + u;
        if (i < n) {
            int o = off[i] + pre;
            off[i] = o;
            cur[i] = o;
        }
    }
    if (tile == 0 && t == 0) {
        int s = 0;
        for (int b = 0; b < ntiles; b++) s += tsum[b];
        off[n] = s;
    }
}

__global__ void fill_k(const int* __restrict__ src, const int* __restrict__ dst,
                       int* __restrict__ cur, int* __restrict__ csr, int E) {
    int i = blockIdx.x * blockDim.x + threadIdx.x;
    if (i < E) {
        int d = dst[i];
        int p = atomicAdd(&cur[d], 1);
        csr[p] = src[i];
    }
}

// G[r][:] = dinv[r] * (X[r][:] @ W).  Thread-per-row, W staged in LDS
// (uniform-address ds_read_b128 -> broadcast, conflict-free).
__global__ __launch_bounds__(256) void gemm64_scale_k(
    const float* __restrict__ X, const float* __restrict__ W,
    const float* __restrict__ dinv, float* __restrict__ G, int n) {
    __shared__ float wl[64 * 64];
    int t = threadIdx.x;
#pragma unroll
    for (int u = 0; u < 16; u++) wl[t + 256 * u] = W[t + 256 * u];
    __syncthreads();
    int r = blockIdx.x * 256 + t;
    if (r >= n) return;

    const float4* xp = (const float4*)(X + (size_t)r * 64);
    float4 acc[16];
#pragma unroll
    for (int j = 0; j < 16; j++) acc[j] = make_float4(0.f, 0.f, 0.f, 0.f);

    for (int i = 0; i < 16; i++) {
        float4 xv = xp[i];
#pragma unroll
        for (int c = 0; c < 4; c++) {
            float xk = (c == 0) ? xv.x : (c == 1) ? xv.y : (c == 2) ? xv.z : xv.w;
            const float4* wr = (const float4*)(wl + (i * 4 + c) * 64);
#pragma unroll
            for (int j = 0; j < 16; j++) {
                float4 wv = wr[j];
                acc[j].x = fmaf(xk, wv.x, acc[j].x);
                acc[j].y = fmaf(xk, wv.y, acc[j].y);
                acc[j].z = fmaf(xk, wv.z, acc[j].z);
                acc[j].w = fmaf(xk, wv.w, acc[j].w);
            }
        }
    }
    float sc = dinv[r];
    float4* gp = (float4*)(G + (size_t)r * 64);
#pragma unroll
    for (int j = 0; j < 16; j++) {
        float4 v = acc[j];
        v.x *= sc; v.y *= sc; v.z *= sc; v.w *= sc;
        gp[j] = v;
    }
}

// Wave-per-node aggregation. lane = feature. G already has dinv[s] folded in.
// FINAL=0: Out[node][lane] = relu(dinv*acc + bias[lane])
// FINAL=1: Out[node] = relu(...) . Wl + bl   (wave reduce)
template <int FINAL>
__global__ __launch_bounds__(256) void agg_k(
    const float* __restrict__ G, const int* __restrict__ csr,
    const int* __restrict__ off, const float* __restrict__ dinv,
    const float* __restrict__ bias, const float* __restrict__ Wl,
    const float* __restrict__ bl, float* __restrict__ Out, int n) {
    int lane = threadIdx.x & 63;
    int wid = threadIdx.x >> 6;
    int node = blockIdx.x * 4 + wid;
    if (node >= n) return;

    float acc = G[(size_t)node * 64 + lane];  // self-loop term (dinv[i]*t[i])
    int s0 = off[node], s1 = off[node + 1];
    for (int base = s0; base < s1; base += 64) {
        int m = s1 - base;
        if (m > 64) m = 64;
        int s = (lane < m) ? csr[base + lane] : 0;
        for (int u = 0; u < m; u++) {
            int sn = __shfl(s, u);
            acc += G[(size_t)sn * 64 + lane];
        }
    }
    float di = dinv[node];
    float v = fmaf(di, acc, bias[lane]);
    v = fmaxf(v, 0.f);
    if (FINAL) {
        float p = v * Wl[lane];
#pragma unroll
        for (int d = 32; d > 0; d >>= 1) p += __shfl_xor(p, d);
        if (lane == 0) Out[node] = p + bl[0];
    } else {
        Out[(size_t)node * 64 + lane] = v;
    }
}

extern "C" void kernel_launch(void* const* d_in, const int* in_sizes, int n_in,
                              void* d_out, int out_size, void* d_ws, size_t ws_size,
                              hipStream_t stream) {
    const float* x  = (const float*)d_in[0];
    const int*   ei = (const int*)d_in[1];
    const float* W1 = (const float*)d_in[2];
    const float* b1 = (const float*)d_in[3];
    const float* W2 = (const float*)d_in[4];
    const float* b2 = (const float*)d_in[5];
    const float* Wl = (const float*)d_in[6];
    const float* bl = (const float*)d_in[7];

    const int N = in_sizes[0] / 64;
    const int E = in_sizes[1] / 2;
    const int* src = ei;
    const int* dst = ei + E;

    char* w = (char*)d_ws;
    size_t o = 0;
    auto take = [&](size_t bytes) {
        void* p = w + o;
        o = (o + bytes + 255) & ~(size_t)255;
        return p;
    };
    const int TILE = 2048;
    const int NT = (N + TILE - 1) / TILE;
    int*   cnt  = (int*)take((size_t)N * 4);         // histogram, later reused as cur
    int*   off  = (int*)take((size_t)(N + 1) * 4);
    float* dinv = (float*)take((size_t)N * 4);
    int*   tsum = (int*)take((size_t)NT * 4);
    int*   csr  = (int*)take((size_t)E * 4);
    float* bufA = (float*)take((size_t)N * 64 * 4);
    float* bufB = (float*)take((size_t)N * 64 * 4);

    hipMemsetAsync(cnt, 0, (size_t)N * 4, stream);
    hist_k<<<(E + 255) / 256, 256, 0, stream>>>(dst, cnt, E);
    dinv_k<<<(N + 255) / 256, 256, 0, stream>>>(cnt, dinv, N);
    scan1_k<<<NT, 256, 0, stream>>>(cnt, off, tsum, N);
    scan2_k<<<NT, 256, 0, stream>>>(off, cnt /*cur*/, tsum, N, NT);
    fill_k<<<(E + 255) / 256, 256, 0, stream>>>(src, dst, cnt, csr, E);

    // Layer 1
    gemm64_scale_k<<<(N + 255) / 256, 256, 0, stream>>>(x, W1, dinv, bufA, N);
    agg_k<0><<<(N + 3) / 4, 256, 0, stream>>>(bufA, csr, off, dinv, b1, nullptr,
                                              nullptr, bufB, N);
    // Layer 2 + fused linear head
    gemm64_scale_k<<<(N + 255) / 256, 256, 0, stream>>>(bufB, W2, dinv, bufA, N);
    agg_k<1><<<(N + 3) / 4, 256, 0, stream>>>(bufA, csr, off, dinv, b2, Wl, bl,
                                              (float*)d_out, N);
}